// Round 1
// baseline (944.307 us; speedup 1.0000x reference)
//
#include <hip/hip_runtime.h>
#include <cstddef>
#include <cstdint>

#define NBLK(n, b) (((n) + (b) - 1) / (b))

static constexpr int IN_CH = 128;

// ---------------- setup kernels ----------------

// Detect whether edge_index is int64 (odd 32-bit words of first 16 values all
// zero, since node ids < 2^17) or int32. Written to ws flag; all later kernels
// branch uniformly on it.
__global__ void k_detect(const unsigned* __restrict__ edges, int* __restrict__ flag) {
  if (threadIdx.x == 0 && blockIdx.x == 0) {
    int is64 = 1;
#pragma unroll
    for (int i = 0; i < 16; ++i)
      if (edges[2 * i + 1] != 0u) is64 = 0;
    *flag = is64;
  }
}

__global__ void k_zero_int(int* __restrict__ p, int n) {
  int i = blockIdx.x * blockDim.x + threadIdx.x;
  if (i < n) p[i] = 0;
}

__global__ void k_hist(const void* __restrict__ edges, const int* __restrict__ flag,
                       int* __restrict__ deg, int E) {
  int e = blockIdx.x * blockDim.x + threadIdx.x;
  if (e >= E) return;
  int d;
  if (*flag) d = (int)((const long long*)edges)[(size_t)E + e];
  else       d = ((const int*)edges)[(size_t)E + e];
  atomicAdd(&deg[d], 1);
}

// Block-level exclusive scan: 256 threads x 4 items = 1024 elems/block.
__global__ void k_scan1(const int* __restrict__ deg, int* __restrict__ rowptr,
                        int* __restrict__ partials, int n) {
  __shared__ int sd[256];
  int t = threadIdx.x;
  int base = blockIdx.x * 1024 + t * 4;
  int v[4];
  int sum = 0;
#pragma unroll
  for (int i = 0; i < 4; ++i) {
    int idx = base + i;
    v[i] = (idx < n) ? deg[idx] : 0;
    sum += v[i];
  }
  sd[t] = sum;
  __syncthreads();
  for (int off = 1; off < 256; off <<= 1) {
    int xv = (t >= off) ? sd[t - off] : 0;
    __syncthreads();
    sd[t] += xv;
    __syncthreads();
  }
  int run = sd[t] - sum;  // exclusive prefix of this thread within block
#pragma unroll
  for (int i = 0; i < 4; ++i) {
    int idx = base + i;
    if (idx < n) rowptr[idx] = run;
    run += v[i];
  }
  if (t == 0) partials[blockIdx.x] = sd[255];
}

__global__ void k_scan2(int* __restrict__ partials, int nb) {
  __shared__ int sd[256];
  int t = threadIdx.x;
  int v = (t < nb) ? partials[t] : 0;
  sd[t] = v;
  __syncthreads();
  for (int off = 1; off < 256; off <<= 1) {
    int xv = (t >= off) ? sd[t - off] : 0;
    __syncthreads();
    sd[t] += xv;
    __syncthreads();
  }
  if (t < nb) partials[t] = sd[t] - v;  // exclusive
}

__global__ void k_scan_add(int* __restrict__ rowptr, int* __restrict__ cursor,
                           const int* __restrict__ partials, int n, int E) {
  int i = blockIdx.x * blockDim.x + threadIdx.x;
  if (i < n) {
    int v = rowptr[i] + partials[i >> 10];
    rowptr[i] = v;
    cursor[i] = v;
  }
  if (blockIdx.x == 0 && threadIdx.x == 0) rowptr[n] = E;
}

__global__ void k_fill(const void* __restrict__ edges, const int* __restrict__ flag,
                       int* __restrict__ cursor, int* __restrict__ srcSorted, int E) {
  int e = blockIdx.x * blockDim.x + threadIdx.x;
  if (e >= E) return;
  int s, d;
  if (*flag) {
    const long long* p = (const long long*)edges;
    s = (int)p[e];
    d = (int)p[(size_t)E + e];
  } else {
    const int* p = (const int*)edges;
    s = p[e];
    d = p[(size_t)E + e];
  }
  int pos = atomicAdd(&cursor[d], 1);
  srcSorted[pos] = s;
}

// ---------------- aggregation: mean over in-neighbors ----------------
// One wave per node; 64 lanes x float2 = 128 channels. Source rows are 512 B
// contiguous -> fully coalesced; rows live in L3 (51.2 MB table).
__global__ void k_aggregate(const float* __restrict__ in, const int* __restrict__ rowptr,
                            const int* __restrict__ srcs, float* __restrict__ mean, int n) {
  int lane = threadIdx.x & 63;
  int w = threadIdx.x >> 6;
  int node = blockIdx.x * 4 + w;
  if (node >= n) return;
  int r0 = rowptr[node], r1 = rowptr[node + 1];
  float ax = 0.f, ay = 0.f;
  for (int base = r0; base < r1; base += 64) {
    int e = base + lane;
    int sv = (e < r1) ? srcs[e] : 0;
    int cnt = min(64, r1 - base);
    for (int j = 0; j < cnt; ++j) {
      int s = __shfl(sv, j);
      float2 xv = *(const float2*)(in + (size_t)s * IN_CH + lane * 2);
      ax += xv.x;
      ay += xv.y;
    }
  }
  float scale = 1.0f / (float)max(r1 - r0, 1);
  *(float2*)(mean + (size_t)node * IN_CH + lane * 2) = make_float2(ax * scale, ay * scale);
}

// ---------------- fused SAGE linear: out = mean@Wl.T + self@Wr.T + b ----------------
// Block = 256 threads, tile = 64 nodes x H cols. K chunked by 32 through LDS.
// LDS transposed layouts give ds_read_b128-friendly inner loop.
template <int H, bool RELU>
__global__ __launch_bounds__(256) void k_gemm(
    const float* __restrict__ self, const float* __restrict__ mean,
    const float* __restrict__ Wl, const float* __restrict__ Wr,
    const float* __restrict__ bias, float* __restrict__ out, int n) {
  constexpr int NI = H / 32;          // cols per thread
  __shared__ float sIn[32][64];       // [k][node]
  __shared__ float sW[32][32][NI];    // [k][tj][ni] -> thread reads contiguous NI
  int t = threadIdx.x;
  int tj = t & 31, tm = t >> 5;       // tm in [0,8): node group of 8
  int nodeBase = blockIdx.x * 64;
  float acc[8][NI];
#pragma unroll
  for (int mi = 0; mi < 8; ++mi)
#pragma unroll
    for (int ni = 0; ni < NI; ++ni) acc[mi][ni] = 0.f;

#pragma unroll
  for (int pass = 0; pass < 2; ++pass) {
    const float* src = pass ? mean : self;
    const float* W = pass ? Wl : Wr;   // Wr pairs with self, Wl with mean
    for (int k0 = 0; k0 < 128; k0 += 32) {
      __syncthreads();
      // stage input tile: 64 nodes x 32 k = 512 float4 slots
#pragma unroll
      for (int i = 0; i < 2; ++i) {
        int s = t + i * 256;
        int nn = s >> 3, kv = s & 7;
        int node = nodeBase + nn;
        float4 v = make_float4(0.f, 0.f, 0.f, 0.f);
        if (node < n) v = *(const float4*)(src + (size_t)node * 128 + k0 + kv * 4);
        int kk = kv * 4;
        sIn[kk + 0][nn] = v.x;
        sIn[kk + 1][nn] = v.y;
        sIn[kk + 2][nn] = v.z;
        sIn[kk + 3][nn] = v.w;
      }
      // stage W tile: H rows x 32 k = H*8 float4 slots
#pragma unroll
      for (int i = 0; i < NI; ++i) {
        int s = t + i * 256;
        int j = s >> 3, kv = s & 7;
        float4 v = *(const float4*)(W + (size_t)j * 128 + k0 + kv * 4);
        int kk = kv * 4;
        int tjj = j & 31, nii = j >> 5;
        sW[kk + 0][tjj][nii] = v.x;
        sW[kk + 1][tjj][nii] = v.y;
        sW[kk + 2][tjj][nii] = v.z;
        sW[kk + 3][tjj][nii] = v.w;
      }
      __syncthreads();
#pragma unroll 4
      for (int kk = 0; kk < 32; ++kk) {
        const float4* ap = (const float4*)&sIn[kk][tm * 8];
        float4 a0 = ap[0], a1 = ap[1];
        float a[8] = {a0.x, a0.y, a0.z, a0.w, a1.x, a1.y, a1.z, a1.w};
        float wv[NI];
        if constexpr (NI == 4) {
          float4 wq = *(const float4*)&sW[kk][tj][0];
          wv[0] = wq.x; wv[1] = wq.y; wv[2] = wq.z; wv[3] = wq.w;
        } else {
          float2 wq = *(const float2*)&sW[kk][tj][0];
          wv[0] = wq.x; wv[1] = wq.y;
        }
#pragma unroll
        for (int mi = 0; mi < 8; ++mi)
#pragma unroll
          for (int ni = 0; ni < NI; ++ni) acc[mi][ni] += a[mi] * wv[ni];
      }
    }
  }
  float bb[NI];
#pragma unroll
  for (int ni = 0; ni < NI; ++ni) bb[ni] = bias[tj + ni * 32];
#pragma unroll
  for (int mi = 0; mi < 8; ++mi) {
    int node = nodeBase + tm * 8 + mi;
    if (node < n) {
#pragma unroll
      for (int ni = 0; ni < NI; ++ni) {
        float vv = acc[mi][ni] + bb[ni];
        if (RELU) vv = fmaxf(vv, 0.f);
        out[(size_t)node * H + tj + ni * 32] = vv;
      }
    }
  }
}

// ---------------- launch ----------------

extern "C" void kernel_launch(void* const* d_in, const int* in_sizes, int n_in,
                              void* d_out, int out_size, void* d_ws, size_t ws_size,
                              hipStream_t stream) {
  (void)n_in; (void)out_size; (void)ws_size;
  const float* x = (const float*)d_in[0];
  const void* edges = d_in[1];
  const float* W1l = (const float*)d_in[2];
  const float* W1r = (const float*)d_in[3];
  const float* b1 = (const float*)d_in[4];
  const float* W2l = (const float*)d_in[5];
  const float* W2r = (const float*)d_in[6];
  const float* b2 = (const float*)d_in[7];
  const float* W3l = (const float*)d_in[8];
  const float* W3r = (const float*)d_in[9];
  const float* b3 = (const float*)d_in[10];
  float* out = (float*)d_out;

  const int N = in_sizes[0] / 128;
  const int E = in_sizes[1] / 2;

  char* ws = (char*)d_ws;
  size_t off = 0;
  auto alloc = [&](size_t bytes) -> char* {
    char* p = ws + off;
    off = (off + bytes + 255) & ~(size_t)255;
    return p;
  };
  int* flag = (int*)alloc(4);
  int* deg = (int*)alloc((size_t)N * 4);
  int* rowptr = (int*)alloc((size_t)(N + 1) * 4);
  int* cursor = (int*)alloc((size_t)N * 4);
  int* partials = (int*)alloc(4096);
  int* srcSorted = (int*)alloc((size_t)E * 4);
  float* mean = (float*)alloc((size_t)N * 128 * 4);
  float* h1 = (float*)alloc((size_t)N * 128 * 4);
  float* h2 = (float*)alloc((size_t)N * 128 * 4);

  int nb1 = (N + 1023) / 1024;

  k_detect<<<1, 64, 0, stream>>>((const unsigned*)edges, flag);
  k_zero_int<<<NBLK(N, 256), 256, 0, stream>>>(deg, N);
  k_hist<<<NBLK(E, 256), 256, 0, stream>>>(edges, flag, deg, E);
  k_scan1<<<nb1, 256, 0, stream>>>(deg, rowptr, partials, N);
  k_scan2<<<1, 256, 0, stream>>>(partials, nb1);
  k_scan_add<<<NBLK(N, 256), 256, 0, stream>>>(rowptr, cursor, partials, N, E);
  k_fill<<<NBLK(E, 256), 256, 0, stream>>>(edges, flag, cursor, srcSorted, E);

  int gAgg = NBLK(N, 4);
  int gGemm = NBLK(N, 64);

  // layer 1
  k_aggregate<<<gAgg, 256, 0, stream>>>(x, rowptr, srcSorted, mean, N);
  k_gemm<128, true><<<gGemm, 256, 0, stream>>>(x, mean, W1l, W1r, b1, h1, N);
  // layer 2
  k_aggregate<<<gAgg, 256, 0, stream>>>(h1, rowptr, srcSorted, mean, N);
  k_gemm<128, true><<<gGemm, 256, 0, stream>>>(h1, mean, W2l, W2r, b2, h2, N);
  // layer 3
  k_aggregate<<<gAgg, 256, 0, stream>>>(h2, rowptr, srcSorted, mean, N);
  k_gemm<64, false><<<gGemm, 256, 0, stream>>>(h2, mean, W3l, W3r, b3, out, N);
}

// Round 2
// 663.521 us; speedup vs baseline: 1.4232x; 1.4232x over previous
//
#include <hip/hip_runtime.h>
#include <hip/hip_bf16.h>
#include <cstddef>
#include <cstdint>

#define NBLK(n, b) (((n) + (b) - 1) / (b))

typedef __attribute__((ext_vector_type(8))) short short8;
typedef __attribute__((ext_vector_type(4))) float f32x4;

__device__ inline unsigned short f2bf(float f) {
  union { float f; unsigned u; } v; v.f = f;
  unsigned u = v.u;
  u += 0x7FFFu + ((u >> 16) & 1u);  // RNE
  return (unsigned short)(u >> 16);
}
__device__ inline float bflo(unsigned u) { union { unsigned u; float f; } v; v.u = u << 16; return v.f; }
__device__ inline float bfhi(unsigned u) { union { unsigned u; float f; } v; v.u = u & 0xFFFF0000u; return v.f; }

// ---------------- setup kernels ----------------

__global__ void k_detect(const unsigned* __restrict__ edges, int* __restrict__ flag) {
  if (threadIdx.x == 0 && blockIdx.x == 0) {
    int is64 = 1;
#pragma unroll
    for (int i = 0; i < 16; ++i)
      if (edges[2 * i + 1] != 0u) is64 = 0;
    *flag = is64;
  }
}

__global__ void k_zero_int(int* __restrict__ p, int n) {
  int i = blockIdx.x * blockDim.x + threadIdx.x;
  if (i < n) p[i] = 0;
}

__global__ void k_cast(const float* __restrict__ x, unsigned* __restrict__ xb, int total2) {
  int i = blockIdx.x * blockDim.x + threadIdx.x;
  if (i >= total2) return;
  float2 v = *(const float2*)(x + (size_t)i * 2);
  xb[i] = (unsigned)f2bf(v.x) | ((unsigned)f2bf(v.y) << 16);
}

// Wb[n][256] bf16 : row n = [Wr[n][0..128) | Wl[n][0..128)]
__global__ void k_prep_w(const float* __restrict__ Wl, const float* __restrict__ Wr,
                         unsigned short* __restrict__ Wb, int total) {
  int i = blockIdx.x * blockDim.x + threadIdx.x;
  if (i >= total) return;
  int nrow = i >> 8, k = i & 255;
  float v = (k < 128) ? Wr[nrow * 128 + k] : Wl[nrow * 128 + (k - 128)];
  Wb[i] = f2bf(v);
}

// histogram + per-edge rank in one pass (rank written coalesced)
__global__ void k_hist_rank(const void* __restrict__ edges, const int* __restrict__ flag,
                            int* __restrict__ deg, int* __restrict__ rank, int E) {
  int e = blockIdx.x * blockDim.x + threadIdx.x;
  if (e >= E) return;
  int d;
  if (*flag) d = (int)((const long long*)edges)[(size_t)E + e];
  else       d = ((const int*)edges)[(size_t)E + e];
  rank[e] = atomicAdd(&deg[d], 1);
}

// Block-level exclusive scan: 256 threads x 4 items = 1024 elems/block.
__global__ void k_scan1(const int* __restrict__ deg, int* __restrict__ rowptr,
                        int* __restrict__ partials, int n) {
  __shared__ int sd[256];
  int t = threadIdx.x;
  int base = blockIdx.x * 1024 + t * 4;
  int v[4];
  int sum = 0;
#pragma unroll
  for (int i = 0; i < 4; ++i) {
    int idx = base + i;
    v[i] = (idx < n) ? deg[idx] : 0;
    sum += v[i];
  }
  sd[t] = sum;
  __syncthreads();
  for (int off = 1; off < 256; off <<= 1) {
    int xv = (t >= off) ? sd[t - off] : 0;
    __syncthreads();
    sd[t] += xv;
    __syncthreads();
  }
  int run = sd[t] - sum;
#pragma unroll
  for (int i = 0; i < 4; ++i) {
    int idx = base + i;
    if (idx < n) rowptr[idx] = run;
    run += v[i];
  }
  if (t == 0) partials[blockIdx.x] = sd[255];
}

__global__ void k_scan2(int* __restrict__ partials, int nb) {
  __shared__ int sd[256];
  int t = threadIdx.x;
  int v = (t < nb) ? partials[t] : 0;
  sd[t] = v;
  __syncthreads();
  for (int off = 1; off < 256; off <<= 1) {
    int xv = (t >= off) ? sd[t - off] : 0;
    __syncthreads();
    sd[t] += xv;
    __syncthreads();
  }
  if (t < nb) partials[t] = sd[t] - v;
}

__global__ void k_scan_add(int* __restrict__ rowptr, const int* __restrict__ partials, int n, int E) {
  int i = blockIdx.x * blockDim.x + threadIdx.x;
  if (i < n) rowptr[i] += partials[i >> 10];
  if (blockIdx.x == 0 && threadIdx.x == 0) rowptr[n] = E;
}

// atomic-free fill using precomputed ranks
__global__ void k_fill2(const void* __restrict__ edges, const int* __restrict__ flag,
                        const int* __restrict__ rowptr, const int* __restrict__ rank,
                        int* __restrict__ srcSorted, int E) {
  int e = blockIdx.x * blockDim.x + threadIdx.x;
  if (e >= E) return;
  int s, d;
  if (*flag) {
    const long long* p = (const long long*)edges;
    s = (int)p[e];
    d = (int)p[(size_t)E + e];
  } else {
    const int* p = (const int*)edges;
    s = p[e];
    d = p[(size_t)E + e];
  }
  srcSorted[rowptr[d] + rank[e]] = s;
}

// ---------------- aggregation: mean over in-neighbors (bf16 in/out, fp32 acc) ----------------
// One wave per node; 64 lanes x (2 bf16 = 4B) = 128 channels = 256B/row.
__global__ void k_aggregate(const unsigned* __restrict__ in, const int* __restrict__ rowptr,
                            const int* __restrict__ srcs, unsigned* __restrict__ mean, int n) {
  int lane = threadIdx.x & 63;
  int w = threadIdx.x >> 6;
  int node = blockIdx.x * 4 + w;
  if (node >= n) return;
  int r0 = rowptr[node], r1 = rowptr[node + 1];
  float ax = 0.f, ay = 0.f;
  for (int base = r0; base < r1; base += 64) {
    int e = base + lane;
    int sv = (e < r1) ? srcs[e] : 0;
    int cnt = min(64, r1 - base);
    for (int j = 0; j < cnt; ++j) {
      int s = __shfl(sv, j);
      unsigned u = in[(size_t)s * 64 + lane];
      ax += bflo(u);
      ay += bfhi(u);
    }
  }
  float sc = 1.0f / (float)max(r1 - r0, 1);
  mean[(size_t)node * 64 + lane] =
      (unsigned)f2bf(ax * sc) | ((unsigned)f2bf(ay * sc) << 16);
}

// ---------------- MFMA GEMM: out = self@Wr.T + mean@Wl.T + b  (K=256 concat) ----------------
// No LDS: A/B fragments straight from global. Block = 4 waves in 2x2; wave tile
// = 64 nodes x H/2 cols as 4 x (H/32) 16x16x32 tiles. Each frag load covers
// 16 rows x 64B -> full-line efficiency.
template <int H, bool RELU, bool BF16OUT>
__global__ __launch_bounds__(256) void k_gemm(
    const unsigned short* __restrict__ selfB, const unsigned short* __restrict__ meanB,
    const unsigned short* __restrict__ Wb, const float* __restrict__ bias,
    void* __restrict__ outp, int n) {
  constexpr int TN = H / 32;  // col tiles per wave
  int lane = threadIdx.x & 63;
  int w = threadIdx.x >> 6;
  int wr = w & 1, wc = w >> 1;
  int nodeBase = blockIdx.x * 128 + wr * 64;
  int colBase = wc * (H / 2);
  int l15 = lane & 15, quad = lane >> 4;

  f32x4 acc[4][TN];
#pragma unroll
  for (int t = 0; t < 4; ++t)
#pragma unroll
    for (int j = 0; j < TN; ++j) acc[t][j] = (f32x4){0.f, 0.f, 0.f, 0.f};

#pragma unroll
  for (int c = 0; c < 8; ++c) {
    const unsigned short* A = (c < 4) ? selfB : meanB;
    int ko = (c & 3) * 32 + quad * 8;
    short8 af[4], bfr[TN];
#pragma unroll
    for (int t = 0; t < 4; ++t) {
      int row = nodeBase + t * 16 + l15;
      row = min(row, n - 1);
      af[t] = *(const short8*)(A + (size_t)row * 128 + ko);
    }
#pragma unroll
    for (int j = 0; j < TN; ++j) {
      int cn = colBase + j * 16 + l15;
      bfr[j] = *(const short8*)(Wb + (size_t)cn * 256 + c * 32 + quad * 8);
    }
#pragma unroll
    for (int t = 0; t < 4; ++t)
#pragma unroll
      for (int j = 0; j < TN; ++j)
        acc[t][j] = __builtin_amdgcn_mfma_f32_16x16x32_bf16(af[t], bfr[j], acc[t][j], 0, 0, 0);
  }

#pragma unroll
  for (int j = 0; j < TN; ++j) {
    int col = colBase + j * 16 + l15;
    float bv = bias[col];
#pragma unroll
    for (int t = 0; t < 4; ++t) {
#pragma unroll
      for (int r = 0; r < 4; ++r) {
        int row = nodeBase + t * 16 + quad * 4 + r;
        if (row < n) {
          float v = acc[t][j][r] + bv;
          if (RELU) v = fmaxf(v, 0.f);
          if (BF16OUT) ((unsigned short*)outp)[(size_t)row * H + col] = f2bf(v);
          else ((float*)outp)[(size_t)row * H + col] = v;
        }
      }
    }
  }
}

// ---------------- launch ----------------

extern "C" void kernel_launch(void* const* d_in, const int* in_sizes, int n_in,
                              void* d_out, int out_size, void* d_ws, size_t ws_size,
                              hipStream_t stream) {
  (void)n_in; (void)out_size; (void)ws_size;
  const float* x = (const float*)d_in[0];
  const void* edges = d_in[1];
  const float* W1l = (const float*)d_in[2];
  const float* W1r = (const float*)d_in[3];
  const float* b1 = (const float*)d_in[4];
  const float* W2l = (const float*)d_in[5];
  const float* W2r = (const float*)d_in[6];
  const float* b2 = (const float*)d_in[7];
  const float* W3l = (const float*)d_in[8];
  const float* W3r = (const float*)d_in[9];
  const float* b3 = (const float*)d_in[10];
  float* out = (float*)d_out;

  const int N = in_sizes[0] / 128;
  const int E = in_sizes[1] / 2;

  char* ws = (char*)d_ws;
  size_t off = 0;
  auto alloc = [&](size_t bytes) -> char* {
    char* p = ws + off;
    off = (off + bytes + 255) & ~(size_t)255;
    return p;
  };
  int* flag = (int*)alloc(4);
  int* deg = (int*)alloc((size_t)N * 4);
  int* rowptr = (int*)alloc((size_t)(N + 1) * 4);
  int* rank = (int*)alloc((size_t)E * 4);
  int* partials = (int*)alloc(4096);
  int* srcSorted = (int*)alloc((size_t)E * 4);
  unsigned short* xb = (unsigned short*)alloc((size_t)N * 128 * 2);
  unsigned short* mean = (unsigned short*)alloc((size_t)N * 128 * 2);
  unsigned short* h1 = (unsigned short*)alloc((size_t)N * 128 * 2);
  unsigned short* h2 = (unsigned short*)alloc((size_t)N * 128 * 2);
  unsigned short* Wb1 = (unsigned short*)alloc(128 * 256 * 2);
  unsigned short* Wb2 = (unsigned short*)alloc(128 * 256 * 2);
  unsigned short* Wb3 = (unsigned short*)alloc(64 * 256 * 2);

  int nb1 = (N + 1023) / 1024;

  k_detect<<<1, 64, 0, stream>>>((const unsigned*)edges, flag);
  k_zero_int<<<NBLK(N, 256), 256, 0, stream>>>(deg, N);
  k_cast<<<NBLK(N * 64, 256), 256, 0, stream>>>(x, (unsigned*)xb, N * 64);
  k_prep_w<<<NBLK(128 * 256, 256), 256, 0, stream>>>(W1l, W1r, Wb1, 128 * 256);
  k_prep_w<<<NBLK(128 * 256, 256), 256, 0, stream>>>(W2l, W2r, Wb2, 128 * 256);
  k_prep_w<<<NBLK(64 * 256, 256), 256, 0, stream>>>(W3l, W3r, Wb3, 64 * 256);
  k_hist_rank<<<NBLK(E, 256), 256, 0, stream>>>(edges, flag, deg, rank, E);
  k_scan1<<<nb1, 256, 0, stream>>>(deg, rowptr, partials, N);
  k_scan2<<<1, 256, 0, stream>>>(partials, nb1);
  k_scan_add<<<NBLK(N, 256), 256, 0, stream>>>(rowptr, partials, N, E);
  k_fill2<<<NBLK(E, 256), 256, 0, stream>>>(edges, flag, rowptr, rank, srcSorted, E);

  int gAgg = NBLK(N, 4);
  int gGemm = NBLK(N, 128);

  // layer 1
  k_aggregate<<<gAgg, 256, 0, stream>>>((const unsigned*)xb, rowptr, srcSorted, (unsigned*)mean, N);
  k_gemm<128, true, true><<<gGemm, 256, 0, stream>>>(xb, mean, Wb1, b1, h1, N);
  // layer 2
  k_aggregate<<<gAgg, 256, 0, stream>>>((const unsigned*)h1, rowptr, srcSorted, (unsigned*)mean, N);
  k_gemm<128, true, true><<<gGemm, 256, 0, stream>>>(h1, mean, Wb2, b2, h2, N);
  // layer 3
  k_aggregate<<<gAgg, 256, 0, stream>>>((const unsigned*)h2, rowptr, srcSorted, (unsigned*)mean, N);
  k_gemm<64, false, false><<<gGemm, 256, 0, stream>>>(h2, mean, Wb3, b3, out, N);
}

// Round 3
// 522.474 us; speedup vs baseline: 1.8074x; 1.2700x over previous
//
#include <hip/hip_runtime.h>
#include <hip/hip_bf16.h>
#include <cstddef>
#include <cstdint>

#define NBLK(n, b) (((n) + (b) - 1) / (b))

typedef __attribute__((ext_vector_type(8))) short short8;
typedef __attribute__((ext_vector_type(4))) float f32x4;

__device__ inline unsigned short f2bf(float f) {
  union { float f; unsigned u; } v; v.f = f;
  unsigned u = v.u;
  u += 0x7FFFu + ((u >> 16) & 1u);  // RNE
  return (unsigned short)(u >> 16);
}
__device__ inline float bflo(unsigned u) { union { unsigned u; float f; } v; v.u = u << 16; return v.f; }
__device__ inline float bfhi(unsigned u) { union { unsigned u; float f; } v; v.u = u & 0xFFFF0000u; return v.f; }

// ---------------- setup kernels ----------------

__global__ void k_detect(const unsigned* __restrict__ edges, int* __restrict__ flag) {
  if (threadIdx.x == 0 && blockIdx.x == 0) {
    int is64 = 1;
#pragma unroll
    for (int i = 0; i < 16; ++i)
      if (edges[2 * i + 1] != 0u) is64 = 0;
    *flag = is64;
  }
}

__global__ void k_zero_int(int* __restrict__ p, int n) {
  int i = blockIdx.x * blockDim.x + threadIdx.x;
  if (i < n) p[i] = 0;
}

__global__ void k_cast(const float* __restrict__ x, unsigned* __restrict__ xb, int total2) {
  int i = blockIdx.x * blockDim.x + threadIdx.x;
  if (i >= total2) return;
  float2 v = *(const float2*)(x + (size_t)i * 2);
  xb[i] = (unsigned)f2bf(v.x) | ((unsigned)f2bf(v.y) << 16);
}

// Wb[n][256] bf16 : row n = [Wr[n][0..128) | Wl[n][0..128)]
__global__ void k_prep_w(const float* __restrict__ Wl, const float* __restrict__ Wr,
                         unsigned short* __restrict__ Wb, int total) {
  int i = blockIdx.x * blockDim.x + threadIdx.x;
  if (i >= total) return;
  int nrow = i >> 8, k = i & 255;
  float v = (k < 128) ? Wr[nrow * 128 + k] : Wl[nrow * 128 + (k - 128)];
  Wb[i] = f2bf(v);
}

// histogram + per-edge rank in one pass (rank written coalesced)
__global__ void k_hist_rank(const void* __restrict__ edges, const int* __restrict__ flag,
                            int* __restrict__ deg, int* __restrict__ rank, int E) {
  int e = blockIdx.x * blockDim.x + threadIdx.x;
  if (e >= E) return;
  int d;
  if (*flag) d = (int)((const long long*)edges)[(size_t)E + e];
  else       d = ((const int*)edges)[(size_t)E + e];
  rank[e] = atomicAdd(&deg[d], 1);
}

// Block-level exclusive scan: 256 threads x 4 items = 1024 elems/block.
__global__ void k_scan1(const int* __restrict__ deg, int* __restrict__ rowptr,
                        int* __restrict__ partials, int n) {
  __shared__ int sd[256];
  int t = threadIdx.x;
  int base = blockIdx.x * 1024 + t * 4;
  int v[4];
  int sum = 0;
#pragma unroll
  for (int i = 0; i < 4; ++i) {
    int idx = base + i;
    v[i] = (idx < n) ? deg[idx] : 0;
    sum += v[i];
  }
  sd[t] = sum;
  __syncthreads();
  for (int off = 1; off < 256; off <<= 1) {
    int xv = (t >= off) ? sd[t - off] : 0;
    __syncthreads();
    sd[t] += xv;
    __syncthreads();
  }
  int run = sd[t] - sum;
#pragma unroll
  for (int i = 0; i < 4; ++i) {
    int idx = base + i;
    if (idx < n) rowptr[idx] = run;
    run += v[i];
  }
  if (t == 0) partials[blockIdx.x] = sd[255];
}

__global__ void k_scan2(int* __restrict__ partials, int nb) {
  __shared__ int sd[256];
  int t = threadIdx.x;
  int v = (t < nb) ? partials[t] : 0;
  sd[t] = v;
  __syncthreads();
  for (int off = 1; off < 256; off <<= 1) {
    int xv = (t >= off) ? sd[t - off] : 0;
    __syncthreads();
    sd[t] += xv;
    __syncthreads();
  }
  if (t < nb) partials[t] = sd[t] - v;
}

__global__ void k_scan_add(int* __restrict__ rowptr, const int* __restrict__ partials, int n, int E) {
  int i = blockIdx.x * blockDim.x + threadIdx.x;
  if (i < n) rowptr[i] += partials[i >> 10];
  if (blockIdx.x == 0 && threadIdx.x == 0) rowptr[n] = E;
}

// atomic-free fill using precomputed ranks
__global__ void k_fill2(const void* __restrict__ edges, const int* __restrict__ flag,
                        const int* __restrict__ rowptr, const int* __restrict__ rank,
                        int* __restrict__ srcSorted, int E) {
  int e = blockIdx.x * blockDim.x + threadIdx.x;
  if (e >= E) return;
  int s, d;
  if (*flag) {
    const long long* p = (const long long*)edges;
    s = (int)p[e];
    d = (int)p[(size_t)E + e];
  } else {
    const int* p = (const int*)edges;
    s = p[e];
    d = p[(size_t)E + e];
  }
  srcSorted[rowptr[d] + rank[e]] = s;
}

// ---------------- aggregation: mean over in-neighbors (bf16 in/out, fp32 acc) ----------------
// One wave per node. Lane = (eg in [0,4)) x (sub in [0,16)): 4 edge rows loaded
// per 16B/lane instruction (1 KB/wave in flight), main loop unrolled x2 (8 edges,
// 2 independent dwordx4 loads). Cross-eg reduction via 2 shfl_downs at the end.
__global__ void k_aggregate(const unsigned* __restrict__ in, const int* __restrict__ rowptr,
                            const int* __restrict__ srcs, unsigned* __restrict__ mean, int n) {
  int lane = threadIdx.x & 63;
  int w = threadIdx.x >> 6;
  int node = blockIdx.x * 4 + w;
  if (node >= n) return;
  int r0 = rowptr[node], r1 = rowptr[node + 1];
  int sub = lane & 15;  // channel group: 8 channels (16 B)
  int eg = lane >> 4;   // edge slot 0..3
  float acc[8];
#pragma unroll
  for (int k = 0; k < 8; ++k) acc[k] = 0.f;

  for (int base = r0; base < r1; base += 64) {
    int e = base + lane;
    int sv = (e < r1) ? srcs[e] : 0;
    int cnt = min(64, r1 - base);
    int j = 0;
    for (; j + 8 <= cnt; j += 8) {
      int s0 = __shfl(sv, j + eg);
      int s1 = __shfl(sv, j + 4 + eg);
      uint4 u0 = *(const uint4*)(in + (size_t)s0 * 64 + sub * 4);
      uint4 u1 = *(const uint4*)(in + (size_t)s1 * 64 + sub * 4);
      acc[0] += bflo(u0.x); acc[1] += bfhi(u0.x);
      acc[2] += bflo(u0.y); acc[3] += bfhi(u0.y);
      acc[4] += bflo(u0.z); acc[5] += bfhi(u0.z);
      acc[6] += bflo(u0.w); acc[7] += bfhi(u0.w);
      acc[0] += bflo(u1.x); acc[1] += bfhi(u1.x);
      acc[2] += bflo(u1.y); acc[3] += bfhi(u1.y);
      acc[4] += bflo(u1.z); acc[5] += bfhi(u1.z);
      acc[6] += bflo(u1.w); acc[7] += bfhi(u1.w);
    }
    for (; j < cnt; j += 4) {
      int jj = j + eg;
      int s = __shfl(sv, jj);
      if (jj < cnt) {
        uint4 u = *(const uint4*)(in + (size_t)s * 64 + sub * 4);
        acc[0] += bflo(u.x); acc[1] += bfhi(u.x);
        acc[2] += bflo(u.y); acc[3] += bfhi(u.y);
        acc[4] += bflo(u.z); acc[5] += bfhi(u.z);
        acc[6] += bflo(u.w); acc[7] += bfhi(u.w);
      }
    }
  }

#pragma unroll
  for (int k = 0; k < 8; ++k) {
    acc[k] += __shfl_down(acc[k], 32);
    acc[k] += __shfl_down(acc[k], 16);
  }
  if (eg == 0) {
    float sc = 1.0f / (float)max(r1 - r0, 1);
    uint4 o;
    o.x = (unsigned)f2bf(acc[0] * sc) | ((unsigned)f2bf(acc[1] * sc) << 16);
    o.y = (unsigned)f2bf(acc[2] * sc) | ((unsigned)f2bf(acc[3] * sc) << 16);
    o.z = (unsigned)f2bf(acc[4] * sc) | ((unsigned)f2bf(acc[5] * sc) << 16);
    o.w = (unsigned)f2bf(acc[6] * sc) | ((unsigned)f2bf(acc[7] * sc) << 16);
    *(uint4*)(mean + (size_t)node * 64 + sub * 4) = o;
  }
}

// ---------------- MFMA GEMM: out = self@Wr.T + mean@Wl.T + b  (K=256 concat) ----------------
template <int H, bool RELU, bool BF16OUT>
__global__ __launch_bounds__(256) void k_gemm(
    const unsigned short* __restrict__ selfB, const unsigned short* __restrict__ meanB,
    const unsigned short* __restrict__ Wb, const float* __restrict__ bias,
    void* __restrict__ outp, int n) {
  constexpr int TN = H / 32;  // col tiles per wave
  int lane = threadIdx.x & 63;
  int w = threadIdx.x >> 6;
  int wr = w & 1, wc = w >> 1;
  int nodeBase = blockIdx.x * 128 + wr * 64;
  int colBase = wc * (H / 2);
  int l15 = lane & 15, quad = lane >> 4;

  f32x4 acc[4][TN];
#pragma unroll
  for (int t = 0; t < 4; ++t)
#pragma unroll
    for (int j = 0; j < TN; ++j) acc[t][j] = (f32x4){0.f, 0.f, 0.f, 0.f};

#pragma unroll
  for (int c = 0; c < 8; ++c) {
    const unsigned short* A = (c < 4) ? selfB : meanB;
    int ko = (c & 3) * 32 + quad * 8;
    short8 af[4], bfr[TN];
#pragma unroll
    for (int t = 0; t < 4; ++t) {
      int row = nodeBase + t * 16 + l15;
      row = min(row, n - 1);
      af[t] = *(const short8*)(A + (size_t)row * 128 + ko);
    }
#pragma unroll
    for (int j = 0; j < TN; ++j) {
      int cn = colBase + j * 16 + l15;
      bfr[j] = *(const short8*)(Wb + (size_t)cn * 256 + c * 32 + quad * 8);
    }
#pragma unroll
    for (int t = 0; t < 4; ++t)
#pragma unroll
      for (int j = 0; j < TN; ++j)
        acc[t][j] = __builtin_amdgcn_mfma_f32_16x16x32_bf16(af[t], bfr[j], acc[t][j], 0, 0, 0);
  }

#pragma unroll
  for (int j = 0; j < TN; ++j) {
    int col = colBase + j * 16 + l15;
    float bv = bias[col];
#pragma unroll
    for (int t = 0; t < 4; ++t) {
#pragma unroll
      for (int r = 0; r < 4; ++r) {
        int row = nodeBase + t * 16 + quad * 4 + r;
        if (row < n) {
          float v = acc[t][j][r] + bv;
          if (RELU) v = fmaxf(v, 0.f);
          if (BF16OUT) ((unsigned short*)outp)[(size_t)row * H + col] = f2bf(v);
          else ((float*)outp)[(size_t)row * H + col] = v;
        }
      }
    }
  }
}

// ---------------- launch ----------------

extern "C" void kernel_launch(void* const* d_in, const int* in_sizes, int n_in,
                              void* d_out, int out_size, void* d_ws, size_t ws_size,
                              hipStream_t stream) {
  (void)n_in; (void)out_size; (void)ws_size;
  const float* x = (const float*)d_in[0];
  const void* edges = d_in[1];
  const float* W1l = (const float*)d_in[2];
  const float* W1r = (const float*)d_in[3];
  const float* b1 = (const float*)d_in[4];
  const float* W2l = (const float*)d_in[5];
  const float* W2r = (const float*)d_in[6];
  const float* b2 = (const float*)d_in[7];
  const float* W3l = (const float*)d_in[8];
  const float* W3r = (const float*)d_in[9];
  const float* b3 = (const float*)d_in[10];
  float* out = (float*)d_out;

  const int N = in_sizes[0] / 128;
  const int E = in_sizes[1] / 2;

  char* ws = (char*)d_ws;
  size_t off = 0;
  auto alloc = [&](size_t bytes) -> char* {
    char* p = ws + off;
    off = (off + bytes + 255) & ~(size_t)255;
    return p;
  };
  int* flag = (int*)alloc(4);
  int* deg = (int*)alloc((size_t)N * 4);
  int* rowptr = (int*)alloc((size_t)(N + 1) * 4);
  int* rank = (int*)alloc((size_t)E * 4);
  int* partials = (int*)alloc(4096);
  int* srcSorted = (int*)alloc((size_t)E * 4);
  unsigned short* xb = (unsigned short*)alloc((size_t)N * 128 * 2);
  unsigned short* mean = (unsigned short*)alloc((size_t)N * 128 * 2);
  unsigned short* h1 = (unsigned short*)alloc((size_t)N * 128 * 2);
  unsigned short* h2 = (unsigned short*)alloc((size_t)N * 128 * 2);
  unsigned short* Wb1 = (unsigned short*)alloc(128 * 256 * 2);
  unsigned short* Wb2 = (unsigned short*)alloc(128 * 256 * 2);
  unsigned short* Wb3 = (unsigned short*)alloc(64 * 256 * 2);

  int nb1 = (N + 1023) / 1024;

  k_detect<<<1, 64, 0, stream>>>((const unsigned*)edges, flag);
  k_zero_int<<<NBLK(N, 256), 256, 0, stream>>>(deg, N);
  k_cast<<<NBLK(N * 64, 256), 256, 0, stream>>>(x, (unsigned*)xb, N * 64);
  k_prep_w<<<NBLK(128 * 256, 256), 256, 0, stream>>>(W1l, W1r, Wb1, 128 * 256);
  k_prep_w<<<NBLK(128 * 256, 256), 256, 0, stream>>>(W2l, W2r, Wb2, 128 * 256);
  k_prep_w<<<NBLK(64 * 256, 256), 256, 0, stream>>>(W3l, W3r, Wb3, 64 * 256);
  k_hist_rank<<<NBLK(E, 256), 256, 0, stream>>>(edges, flag, deg, rank, E);
  k_scan1<<<nb1, 256, 0, stream>>>(deg, rowptr, partials, N);
  k_scan2<<<1, 256, 0, stream>>>(partials, nb1);
  k_scan_add<<<NBLK(N, 256), 256, 0, stream>>>(rowptr, partials, N, E);
  k_fill2<<<NBLK(E, 256), 256, 0, stream>>>(edges, flag, rowptr, rank, srcSorted, E);

  int gAgg = NBLK(N, 4);
  int gGemm = NBLK(N, 128);

  // layer 1
  k_aggregate<<<gAgg, 256, 0, stream>>>((const unsigned*)xb, rowptr, srcSorted, (unsigned*)mean, N);
  k_gemm<128, true, true><<<gGemm, 256, 0, stream>>>(xb, mean, Wb1, b1, h1, N);
  // layer 2
  k_aggregate<<<gAgg, 256, 0, stream>>>((const unsigned*)h1, rowptr, srcSorted, (unsigned*)mean, N);
  k_gemm<128, true, true><<<gGemm, 256, 0, stream>>>(h1, mean, Wb2, b2, h2, N);
  // layer 3
  k_aggregate<<<gAgg, 256, 0, stream>>>((const unsigned*)h2, rowptr, srcSorted, (unsigned*)mean, N);
  k_gemm<64, false, false><<<gGemm, 256, 0, stream>>>(h2, mean, Wb3, b3, out, N);
}